// Round 1
// baseline (2768.958 us; speedup 1.0000x reference)
//
#include <hip/hip_runtime.h>

#define IMG_H 1024
#define IMG_W 1024
#define NPIX  (IMG_H * IMG_W)          // 1048576, log2 = 20 exactly
#define NBINS (256 * 512)              // 131072 joint bins
#define TILE  64
#define LW    (TILE + 2)               // 66 (tile + halo)

// ---------------------------------------------------------------------------
// Pass 1: quantize + 8-neighbor sum + joint-code histogram (global atomics).
// Block = 256 threads handles one 64x64 tile. LDS holds the 66x66 quantized
// halo tile as int. Each thread owns one column (tx) and a 16-row strip (sy),
// rolling 3-wide horizontal sums down the strip: 3 LDS reads / pixel.
// ---------------------------------------------------------------------------
__global__ __launch_bounds__(256) void hist_kernel(const float* __restrict__ x,
                                                   unsigned int* __restrict__ hist,
                                                   int B) {
    __shared__ int s[LW * LW];

    const int tilesPerRow = IMG_W / TILE;                 // 16
    const int tilesPerImg = (IMG_H / TILE) * tilesPerRow; // 256
    const int b   = blockIdx.x / tilesPerImg;
    const int t   = blockIdx.x % tilesPerImg;
    const int ty0 = (t / tilesPerRow) * TILE;
    const int tx0 = (t % tilesPerRow) * TILE;

    const float* img = x + (size_t)b * NPIX;
    const int tid = threadIdx.x;

    // Load 66x66 halo tile, quantize on the fly, zero-pad out-of-image.
    for (int i = tid; i < LW * LW; i += 256) {
        int r  = i / LW;
        int c  = i - r * LW;
        int gy = ty0 + r - 1;
        int gx = tx0 + c - 1;
        int v  = 0;
        if ((unsigned)gy < IMG_H && (unsigned)gx < IMG_W)
            v = (int)(img[gy * IMG_W + gx] * 255.0f);   // trunc, 0..254
        s[i] = v;
    }
    __syncthreads();

    unsigned int* hb = hist + (size_t)b * NBINS;
    const bool bEdge = (b == 0) || (b == B - 1);

    const int tx = tid & 63;        // column within tile
    const int sy = tid >> 6;        // 0..3 -> 16-row strip
    const int c  = tx + 1;          // LDS column (skip halo)
    const int r0 = sy * 16;         // first tile-row of this strip

    // Rolling horizontal sums: h(r) = s[r][c-1]+s[r][c]+s[r][c+1].
    // Pixel at tile-row ry (LDS row ry+1): nb = h(ry)+h(ry+1)+h(ry+2) - center.
    int h0, h1, m1;
    { int a = s[r0 * LW + c - 1], m = s[r0 * LW + c], d = s[r0 * LW + c + 1];
      h0 = a + m + d; }
    { int a = s[(r0 + 1) * LW + c - 1], m = s[(r0 + 1) * LW + c], d = s[(r0 + 1) * LW + c + 1];
      h1 = a + m + d; m1 = m; }

    for (int ry = r0; ry < r0 + 16; ++ry) {
        int a = s[(ry + 2) * LW + c - 1];
        int m = s[(ry + 2) * LW + c];
        int d = s[(ry + 2) * LW + c + 1];
        int h2 = a + m + d;

        int nb = h0 + h1 + h2 - m1;           // 8-neighbor sum (center m1)
        int gy = ty0 + ry;
        // Divisor is 5 everywhere except the 4 (batch,row) corners (=3) —
        // faithful to the reference's batch-indexed normalization quirk.
        // Integer div == trunc(float div) here (no boundary-crossing rounding).
        unsigned mean = (unsigned)nb / 5u;
        if (bEdge && (gy == 0 || gy == IMG_H - 1)) mean = (unsigned)nb / 3u;

        atomicAdd(&hb[m1 * 512 + (int)mean], 1u);

        h0 = h1; h1 = h2; m1 = m;
    }
}

// ---------------------------------------------------------------------------
// Pass 2: entropy partial sums.  -p*log2(p) = (c/N)*(20 - log2 c); we sum
// c*(20 - log2 c) over ALL images' bins (mean over images is a flat 1/(N*B)
// scale at the end), reduce per-block, one double atomicAdd per block.
// ---------------------------------------------------------------------------
__global__ __launch_bounds__(256) void entropy_kernel(const unsigned int* __restrict__ hist,
                                                      double* __restrict__ acc,
                                                      int n) {
    double local = 0.0;
    const int stride = gridDim.x * 256;
    for (int i = blockIdx.x * 256 + threadIdx.x; i < n; i += stride) {
        unsigned int cv = hist[i];
        if (cv) {
            float lc = log2f((float)cv);
            local += (double)cv * (20.0 - (double)lc);
        }
    }
    // wave (64-lane) butterfly reduce
    for (int off = 32; off > 0; off >>= 1)
        local += __shfl_down(local, off, 64);

    __shared__ double sacc[4];
    const int lane = threadIdx.x & 63;
    const int wid  = threadIdx.x >> 6;
    if (lane == 0) sacc[wid] = local;
    __syncthreads();
    if (threadIdx.x == 0) {
        double t = sacc[0] + sacc[1] + sacc[2] + sacc[3];
        atomicAdd(acc, t);
    }
}

__global__ void finalize_kernel(const double* __restrict__ acc,
                                float* __restrict__ out, int B) {
    out[0] = (float)(acc[0] / ((double)NPIX * (double)B));
}

extern "C" void kernel_launch(void* const* d_in, const int* in_sizes, int n_in,
                              void* d_out, int out_size, void* d_ws, size_t ws_size,
                              hipStream_t stream) {
    const float* x = (const float*)d_in[0];
    const int B = in_sizes[0] / NPIX;   // 64

    unsigned int* hist = (unsigned int*)d_ws;
    const size_t histBytes = (size_t)B * NBINS * sizeof(unsigned int); // 32 MB
    double* acc = (double*)((char*)d_ws + histBytes);

    // Zero histograms + accumulator (ws is re-poisoned to 0xAA each call).
    hipMemsetAsync(d_ws, 0, histBytes + sizeof(double), stream);

    const int tilesPerImg = (IMG_H / TILE) * (IMG_W / TILE); // 256
    hist_kernel<<<B * tilesPerImg, 256, 0, stream>>>(x, hist, B);

    entropy_kernel<<<1024, 256, 0, stream>>>(hist, acc, B * NBINS);
    finalize_kernel<<<1, 1, 0, stream>>>(acc, (float*)d_out, B);
}

// Round 2
// 611.396 us; speedup vs baseline: 4.5289x; 4.5289x over previous
//
#include <hip/hip_runtime.h>

#define IMG_H 1024
#define IMG_W 1024
#define NPIX  (IMG_H * IMG_W)          // 1048576, log2 = 20 exactly
#define NBINS (256 * 512)              // joint bins (fallback path)
#define TILE  64
#define LW    (TILE + 2)               // 66 (tile + halo)

#define VPASS  64                      // v-values per LDS pass
#define NPASS  4                       // 256 v-values / 64
#define MEANS  426                     // mean bins per v (max mean = 423), even
#define HWORDS (VPASS * MEANS / 2)     // 13632 u32 words, 2 u16 counts each

// ---------------------------------------------------------------------------
// Fast path, pass A: quantize + 8-neighbor sum -> per-pixel joint code
// (v<<9 | mean), coalesced u32 store. Same tiling as the validated round-1
// kernel (absmax 0), minus the global atomic.
// ---------------------------------------------------------------------------
__global__ __launch_bounds__(256) void code_kernel(const float* __restrict__ x,
                                                   unsigned int* __restrict__ codes,
                                                   int B) {
    __shared__ int s[LW * LW];

    const int tilesPerRow = IMG_W / TILE;                 // 16
    const int tilesPerImg = (IMG_H / TILE) * tilesPerRow; // 256
    const int b   = blockIdx.x / tilesPerImg;
    const int t   = blockIdx.x % tilesPerImg;
    const int ty0 = (t / tilesPerRow) * TILE;
    const int tx0 = (t % tilesPerRow) * TILE;

    const float* img = x + (size_t)b * NPIX;
    const int tid = threadIdx.x;

    for (int i = tid; i < LW * LW; i += 256) {
        int r  = i / LW;
        int c  = i - r * LW;
        int gy = ty0 + r - 1;
        int gx = tx0 + c - 1;
        int v  = 0;
        if ((unsigned)gy < IMG_H && (unsigned)gx < IMG_W)
            v = (int)(img[gy * IMG_W + gx] * 255.0f);   // trunc, 0..254
        s[i] = v;
    }
    __syncthreads();

    unsigned int* cb = codes + (size_t)b * NPIX;
    const bool bEdge = (b == 0) || (b == B - 1);

    const int tx = tid & 63;
    const int sy = tid >> 6;
    const int c  = tx + 1;
    const int r0 = sy * 16;

    int h0, h1, m1;
    { int a = s[r0 * LW + c - 1], m = s[r0 * LW + c], d = s[r0 * LW + c + 1];
      h0 = a + m + d; }
    { int a = s[(r0 + 1) * LW + c - 1], m = s[(r0 + 1) * LW + c], d = s[(r0 + 1) * LW + c + 1];
      h1 = a + m + d; m1 = m; }

    for (int ry = r0; ry < r0 + 16; ++ry) {
        int a = s[(ry + 2) * LW + c - 1];
        int m = s[(ry + 2) * LW + c];
        int d = s[(ry + 2) * LW + c + 1];
        int h2 = a + m + d;

        int nb = h0 + h1 + h2 - m1;           // 8-neighbor sum, center m1
        int gy = ty0 + ry;
        // Divisor 5 everywhere except (batch,row) corners = 3 (reference's
        // batch-indexed normalization quirk). Integer div == float-trunc here.
        unsigned mean = (unsigned)nb / 5u;
        if (bEdge && (gy == 0 || gy == IMG_H - 1)) mean = (unsigned)nb / 3u;

        cb[gy * IMG_W + (tx0 + tx)] = ((unsigned)m1 << 9) | mean;

        h0 = h1; h1 = h2; m1 = m;
    }
}

// ---------------------------------------------------------------------------
// Fast path, pass B: one block per (image, v-range). Scans the image's codes
// with uint4 loads, counts into a u16-packed LDS histogram (u32 ds_atomics,
// carry-safe: max bin count ~40 << 65535), then folds the completed bins
// straight into the entropy sum — no global histogram at all.
// Block mapping b = blk % B keeps an image's 4 pass-blocks on one XCD.
// ---------------------------------------------------------------------------
__global__ __launch_bounds__(1024) void histent_kernel(const unsigned int* __restrict__ codes,
                                                       double* __restrict__ acc,
                                                       int B) {
    __shared__ unsigned int h[HWORDS];
    __shared__ double sacc[16];

    const int b = blockIdx.x % B;
    const int p = blockIdx.x / B;
    const int tid = threadIdx.x;

    for (int i = tid; i < HWORDS; i += 1024) h[i] = 0u;
    __syncthreads();

    const uint4* c4 = (const uint4*)(codes + (size_t)b * NPIX);
    const unsigned pv = (unsigned)p;

    for (int i = tid; i < NPIX / 4; i += 1024) {
        uint4 c = c4[i];
        unsigned v, bin;
        v = c.x >> 9;
        if ((v >> 6) == pv) { bin = (v & 63u) * MEANS + (c.x & 511u);
            atomicAdd(&h[bin >> 1], 1u << ((bin & 1u) * 16u)); }
        v = c.y >> 9;
        if ((v >> 6) == pv) { bin = (v & 63u) * MEANS + (c.y & 511u);
            atomicAdd(&h[bin >> 1], 1u << ((bin & 1u) * 16u)); }
        v = c.z >> 9;
        if ((v >> 6) == pv) { bin = (v & 63u) * MEANS + (c.z & 511u);
            atomicAdd(&h[bin >> 1], 1u << ((bin & 1u) * 16u)); }
        v = c.w >> 9;
        if ((v >> 6) == pv) { bin = (v & 63u) * MEANS + (c.w & 511u);
            atomicAdd(&h[bin >> 1], 1u << ((bin & 1u) * 16u)); }
    }
    __syncthreads();

    // Entropy of completed bins: sum c*(20 - log2 c); scaled by 1/(N*B) later.
    double local = 0.0;
    for (int w = tid; w < HWORDS; w += 1024) {
        unsigned u = h[w];
        unsigned c0 = u & 0xffffu, c1 = u >> 16;
        if (c0) local += (double)c0 * (20.0 - (double)log2f((float)c0));
        if (c1) local += (double)c1 * (20.0 - (double)log2f((float)c1));
    }
    for (int off = 32; off > 0; off >>= 1)
        local += __shfl_down(local, off, 64);

    const int lane = tid & 63;
    const int wid  = tid >> 6;
    if (lane == 0) sacc[wid] = local;
    __syncthreads();
    if (tid == 0) {
        double t = 0.0;
        for (int i = 0; i < 16; ++i) t += sacc[i];
        atomicAdd(acc, t);
    }
}

// ---------------------------------------------------------------------------
// Fallback path (round-1, validated): global-atomic histogram + entropy scan.
// Used only if ws_size can't hold the 256 MB code buffer.
// ---------------------------------------------------------------------------
__global__ __launch_bounds__(256) void hist_kernel(const float* __restrict__ x,
                                                   unsigned int* __restrict__ hist,
                                                   int B) {
    __shared__ int s[LW * LW];

    const int tilesPerRow = IMG_W / TILE;
    const int tilesPerImg = (IMG_H / TILE) * tilesPerRow;
    const int b   = blockIdx.x / tilesPerImg;
    const int t   = blockIdx.x % tilesPerImg;
    const int ty0 = (t / tilesPerRow) * TILE;
    const int tx0 = (t % tilesPerRow) * TILE;

    const float* img = x + (size_t)b * NPIX;
    const int tid = threadIdx.x;

    for (int i = tid; i < LW * LW; i += 256) {
        int r  = i / LW;
        int c  = i - r * LW;
        int gy = ty0 + r - 1;
        int gx = tx0 + c - 1;
        int v  = 0;
        if ((unsigned)gy < IMG_H && (unsigned)gx < IMG_W)
            v = (int)(img[gy * IMG_W + gx] * 255.0f);
        s[i] = v;
    }
    __syncthreads();

    unsigned int* hb = hist + (size_t)b * NBINS;
    const bool bEdge = (b == 0) || (b == B - 1);

    const int tx = tid & 63;
    const int sy = tid >> 6;
    const int c  = tx + 1;
    const int r0 = sy * 16;

    int h0, h1, m1;
    { int a = s[r0 * LW + c - 1], m = s[r0 * LW + c], d = s[r0 * LW + c + 1];
      h0 = a + m + d; }
    { int a = s[(r0 + 1) * LW + c - 1], m = s[(r0 + 1) * LW + c], d = s[(r0 + 1) * LW + c + 1];
      h1 = a + m + d; m1 = m; }

    for (int ry = r0; ry < r0 + 16; ++ry) {
        int a = s[(ry + 2) * LW + c - 1];
        int m = s[(ry + 2) * LW + c];
        int d = s[(ry + 2) * LW + c + 1];
        int h2 = a + m + d;

        int nb = h0 + h1 + h2 - m1;
        int gy = ty0 + ry;
        unsigned mean = (unsigned)nb / 5u;
        if (bEdge && (gy == 0 || gy == IMG_H - 1)) mean = (unsigned)nb / 3u;

        atomicAdd(&hb[m1 * 512 + (int)mean], 1u);

        h0 = h1; h1 = h2; m1 = m;
    }
}

__global__ __launch_bounds__(256) void entropy_kernel(const unsigned int* __restrict__ hist,
                                                      double* __restrict__ acc,
                                                      int n) {
    double local = 0.0;
    const int stride = gridDim.x * 256;
    for (int i = blockIdx.x * 256 + threadIdx.x; i < n; i += stride) {
        unsigned int cv = hist[i];
        if (cv) {
            float lc = log2f((float)cv);
            local += (double)cv * (20.0 - (double)lc);
        }
    }
    for (int off = 32; off > 0; off >>= 1)
        local += __shfl_down(local, off, 64);

    __shared__ double sacc[4];
    const int lane = threadIdx.x & 63;
    const int wid  = threadIdx.x >> 6;
    if (lane == 0) sacc[wid] = local;
    __syncthreads();
    if (threadIdx.x == 0) {
        double t = sacc[0] + sacc[1] + sacc[2] + sacc[3];
        atomicAdd(acc, t);
    }
}

__global__ void finalize_kernel(const double* __restrict__ acc,
                                float* __restrict__ out, int B) {
    out[0] = (float)(acc[0] / ((double)NPIX * (double)B));
}

extern "C" void kernel_launch(void* const* d_in, const int* in_sizes, int n_in,
                              void* d_out, int out_size, void* d_ws, size_t ws_size,
                              hipStream_t stream) {
    const float* x = (const float*)d_in[0];
    const int B = in_sizes[0] / NPIX;   // 64

    const size_t codeBytes = (size_t)B * NPIX * sizeof(unsigned int); // 256 MB
    const int tilesPerImg = (IMG_H / TILE) * (IMG_W / TILE);          // 256

    if (ws_size >= codeBytes + 64) {
        // ---- fast path: codes scratch + LDS histograms ----
        unsigned int* codes = (unsigned int*)d_ws;
        double* acc = (double*)((char*)d_ws + codeBytes);
        hipMemsetAsync(acc, 0, sizeof(double), stream);

        code_kernel<<<B * tilesPerImg, 256, 0, stream>>>(x, codes, B);
        histent_kernel<<<B * NPASS, 1024, 0, stream>>>(codes, acc, B);
        finalize_kernel<<<1, 1, 0, stream>>>(acc, (float*)d_out, B);
    } else {
        // ---- fallback: round-1 validated global-atomic path ----
        unsigned int* hist = (unsigned int*)d_ws;
        const size_t histBytes = (size_t)B * NBINS * sizeof(unsigned int); // 32 MB
        double* acc = (double*)((char*)d_ws + histBytes);

        hipMemsetAsync(d_ws, 0, histBytes + sizeof(double), stream);
        hist_kernel<<<B * tilesPerImg, 256, 0, stream>>>(x, hist, B);
        entropy_kernel<<<1024, 256, 0, stream>>>(hist, acc, B * NBINS);
        finalize_kernel<<<1, 1, 0, stream>>>(acc, (float*)d_out, B);
    }
}

// Round 3
// 482.821 us; speedup vs baseline: 5.7350x; 1.2663x over previous
//
#include <hip/hip_runtime.h>

#define IMG_H 1024
#define IMG_W 1024
#define NPIX  (IMG_H * IMG_W)         // 1048576, log2 = 20 exactly
#define NBINS (256 * 512)             // fallback path bins
#define TILE  64
#define LW    (TILE + 2)

#define MEANS  428                    // mean in [0,424); 428 = 4*107 (u8 word-packed)
#define HBINS  (256 * MEANS)          // 109568 joint bins
#define HWORDS (HBINS / 4)            // 27392 u32 words, 4 u8 counts each
#define QUADS  4
#define QROWS  (IMG_H / QUADS)        // 256 rows per block

// ---------------------------------------------------------------------------
// Fused pass: quantize + 8-neighbor sum + u8-packed LDS joint histogram.
// Grid = B*4 blocks (image x row-quadrant), 1024 threads = 1 thread/column.
// Rolling 3-row vertical window in registers; horizontal neighbors come from
// 2 extra global loads (L1-hit, same cache lines) so the LDS pipe is reserved
// for the histogram atomics. u8 counts are safe: per-quadrant bin lambda ~10,
// Poisson P(>=256) ~ 1e-300. Each block flushes its 27392-word partial.
// ---------------------------------------------------------------------------
__global__ __launch_bounds__(1024) void fused_hist_kernel(const float* __restrict__ x,
                                                          unsigned int* __restrict__ partials,
                                                          int B) {
    __shared__ unsigned int h[HWORDS];

    const int blk  = blockIdx.x;
    const int b    = blk >> 2;
    const int quad = blk & 3;
    const int t    = threadIdx.x;          // column

    for (int i = t; i < HWORDS; i += 1024) h[i] = 0u;
    __syncthreads();

    const float* img = x + (size_t)b * NPIX;
    const int rs = quad * QROWS;
    const bool bEdge = (b == 0) || (b == B - 1);

    const int cl = (t > 0) ? t - 1 : 0;               // clamped addr, value zeroed below
    const int cr = (t < IMG_W - 1) ? t + 1 : IMG_W - 1;

    // load 3 pixels of row r (uniform branch; OOB rows -> 0)
    auto loadrow = [&](int r, float& pL, float& pC, float& pR) {
        if ((unsigned)r < IMG_H) {
            const float* row = img + r * IMG_W;
            pL = row[cl]; pC = row[t]; pR = row[cr];
        } else { pL = 0.0f; pC = 0.0f; pR = 0.0f; }
    };
    // quantize + horizontal 3-sum (zero-pad at image's left/right edges)
    auto qhsum = [&](float pL, float pC, float pR, int& hs, int& qc) {
        int qL = (int)(pL * 255.0f);
        int qC = (int)(pC * 255.0f);
        int qR = (int)(pR * 255.0f);
        if (t == 0)         qL = 0;
        if (t == IMG_W - 1) qR = 0;
        qc = qC; hs = qL + qC + qR;
    };

    // pipeline init: hA=h(rs-1), hB=h(rs)/qB=q(rs), prefetch row rs+1
    int hA, hB, qB;
    { float a, m, c; loadrow(rs - 1, a, m, c); int qq; qhsum(a, m, c, hA, qq); }
    { float a, m, c; loadrow(rs,     a, m, c); qhsum(a, m, c, hB, qB); }
    float nL, nC, nR; loadrow(rs + 1, nL, nC, nR);

    for (int r = rs; r < rs + QROWS; ++r) {
        float cL = nL, cC = nC, cR = nR;
        loadrow(r + 2, nL, nC, nR);                    // prefetch next row
        int hC, qC; qhsum(cL, cC, cR, hC, qC);

        int nb = hA + hB + hC - qB;                    // 8-neighbor sum of (r,t)
        // divisor 5 everywhere except (batch,row) corners = 3 (reference's
        // batch-indexed quirk); integer div == float-trunc here. r is
        // block-uniform -> scalar branch, no divergence.
        unsigned mean;
        if (bEdge && (r == 0 || r == IMG_H - 1)) mean = (unsigned)nb / 3u;
        else                                     mean = (unsigned)nb / 5u;

        unsigned bin = (unsigned)qB * MEANS + mean;
        atomicAdd(&h[bin >> 2], 1u << ((bin & 3u) * 8u));

        hA = hB; hB = hC; qB = qC;
    }
    __syncthreads();

    unsigned int* dst = partials + (size_t)blk * HWORDS;
    for (int i = t; i < HWORDS; i += 1024) dst[i] = h[i];
}

// ---------------------------------------------------------------------------
// Merge the 4 quadrant partials per image (bytewise) + entropy:
// sum c*(20 - log2 c) over bins, scaled by 1/(N*B) in finalize.
// ---------------------------------------------------------------------------
__global__ __launch_bounds__(256) void merge_entropy_kernel(const unsigned int* __restrict__ partials,
                                                            double* __restrict__ acc,
                                                            int B) {
    double local = 0.0;
    const int n = B * HWORDS;
    for (int idx = blockIdx.x * 256 + threadIdx.x; idx < n; idx += gridDim.x * 256) {
        int img = idx / HWORDS;                        // constant-divisor magic
        int w   = idx - img * HWORDS;
        const unsigned int* p = partials + (size_t)img * QUADS * HWORDS + w;
        unsigned w0 = p[0], w1 = p[HWORDS], w2 = p[2 * HWORDS], w3 = p[3 * HWORDS];
#pragma unroll
        for (int sh = 0; sh < 32; sh += 8) {
            unsigned c = ((w0 >> sh) & 255u) + ((w1 >> sh) & 255u)
                       + ((w2 >> sh) & 255u) + ((w3 >> sh) & 255u);
            if (c) local += (double)c * (20.0 - (double)log2f((float)c));
        }
    }
    for (int off = 32; off > 0; off >>= 1)
        local += __shfl_down(local, off, 64);

    __shared__ double sacc[4];
    const int lane = threadIdx.x & 63;
    const int wid  = threadIdx.x >> 6;
    if (lane == 0) sacc[wid] = local;
    __syncthreads();
    if (threadIdx.x == 0)
        atomicAdd(acc, sacc[0] + sacc[1] + sacc[2] + sacc[3]);
}

__global__ void finalize_kernel(const double* __restrict__ acc,
                                float* __restrict__ out, int B) {
    out[0] = (float)(acc[0] / ((double)NPIX * (double)B));
}

// ---------------------------------------------------------------------------
// Fallback (round-1, validated): global-atomic histogram path.
// ---------------------------------------------------------------------------
__global__ __launch_bounds__(256) void hist_kernel(const float* __restrict__ x,
                                                   unsigned int* __restrict__ hist,
                                                   int B) {
    __shared__ int s[LW * LW];
    const int tilesPerRow = IMG_W / TILE;
    const int tilesPerImg = (IMG_H / TILE) * tilesPerRow;
    const int b   = blockIdx.x / tilesPerImg;
    const int t   = blockIdx.x % tilesPerImg;
    const int ty0 = (t / tilesPerRow) * TILE;
    const int tx0 = (t % tilesPerRow) * TILE;
    const float* img = x + (size_t)b * NPIX;
    const int tid = threadIdx.x;

    for (int i = tid; i < LW * LW; i += 256) {
        int r = i / LW, c = i - r * LW;
        int gy = ty0 + r - 1, gx = tx0 + c - 1;
        int v = 0;
        if ((unsigned)gy < IMG_H && (unsigned)gx < IMG_W)
            v = (int)(img[gy * IMG_W + gx] * 255.0f);
        s[i] = v;
    }
    __syncthreads();

    unsigned int* hb = hist + (size_t)b * NBINS;
    const bool bEdge = (b == 0) || (b == B - 1);
    const int tx = tid & 63, sy = tid >> 6;
    const int c = tx + 1, r0 = sy * 16;

    int h0, h1, m1;
    { int a = s[r0 * LW + c - 1], m = s[r0 * LW + c], d = s[r0 * LW + c + 1]; h0 = a + m + d; }
    { int a = s[(r0 + 1) * LW + c - 1], m = s[(r0 + 1) * LW + c], d = s[(r0 + 1) * LW + c + 1]; h1 = a + m + d; m1 = m; }

    for (int ry = r0; ry < r0 + 16; ++ry) {
        int a = s[(ry + 2) * LW + c - 1], m = s[(ry + 2) * LW + c], d = s[(ry + 2) * LW + c + 1];
        int h2 = a + m + d;
        int nb = h0 + h1 + h2 - m1;
        int gy = ty0 + ry;
        unsigned mean = (unsigned)nb / 5u;
        if (bEdge && (gy == 0 || gy == IMG_H - 1)) mean = (unsigned)nb / 3u;
        atomicAdd(&hb[m1 * 512 + (int)mean], 1u);
        h0 = h1; h1 = h2; m1 = m;
    }
}

__global__ __launch_bounds__(256) void entropy_kernel(const unsigned int* __restrict__ hist,
                                                      double* __restrict__ acc, int n) {
    double local = 0.0;
    const int stride = gridDim.x * 256;
    for (int i = blockIdx.x * 256 + threadIdx.x; i < n; i += stride) {
        unsigned int cv = hist[i];
        if (cv) local += (double)cv * (20.0 - (double)log2f((float)cv));
    }
    for (int off = 32; off > 0; off >>= 1)
        local += __shfl_down(local, off, 64);
    __shared__ double sacc[4];
    const int lane = threadIdx.x & 63, wid = threadIdx.x >> 6;
    if (lane == 0) sacc[wid] = local;
    __syncthreads();
    if (threadIdx.x == 0)
        atomicAdd(acc, sacc[0] + sacc[1] + sacc[2] + sacc[3]);
}

extern "C" void kernel_launch(void* const* d_in, const int* in_sizes, int n_in,
                              void* d_out, int out_size, void* d_ws, size_t ws_size,
                              hipStream_t stream) {
    const float* x = (const float*)d_in[0];
    const int B = in_sizes[0] / NPIX;   // 64

    const size_t partBytes = (size_t)B * QUADS * HWORDS * sizeof(unsigned int); // ~28 MB

    if (ws_size >= partBytes + 64) {
        unsigned int* partials = (unsigned int*)d_ws;
        double* acc = (double*)((char*)d_ws + partBytes);
        hipMemsetAsync(acc, 0, sizeof(double), stream);

        fused_hist_kernel<<<B * QUADS, 1024, 0, stream>>>(x, partials, B);
        merge_entropy_kernel<<<256, 256, 0, stream>>>(partials, acc, B);
        finalize_kernel<<<1, 1, 0, stream>>>(acc, (float*)d_out, B);
    } else {
        unsigned int* hist = (unsigned int*)d_ws;
        const size_t histBytes = (size_t)B * NBINS * sizeof(unsigned int);
        double* acc = (double*)((char*)d_ws + histBytes);
        hipMemsetAsync(d_ws, 0, histBytes + sizeof(double), stream);

        const int tilesPerImg = (IMG_H / TILE) * (IMG_W / TILE);
        hist_kernel<<<B * tilesPerImg, 256, 0, stream>>>(x, hist, B);
        entropy_kernel<<<1024, 256, 0, stream>>>(hist, acc, B * NBINS);
        finalize_kernel<<<1, 1, 0, stream>>>(acc, (float*)d_out, B);
    }
}

// Round 4
// 454.613 us; speedup vs baseline: 6.0908x; 1.0620x over previous
//
#include <hip/hip_runtime.h>

#define IMG_H 1024
#define IMG_W 1024
#define NPIX  (IMG_H * IMG_W)         // 1048576, log2 = 20 exactly
#define NBINS (256 * 512)             // fallback path bins
#define TILE  64
#define LW    (TILE + 2)

#define MEANS  428                    // mean in [0,424); 428 = 4*107 (u8 word-packed)
#define HBINS  (256 * MEANS)          // 109568 joint bins
#define HWORDS (HBINS / 4)            // 27392 u32 words, 4 u8 counts each
#define QUADS  4
#define QROWS  (IMG_H / QUADS)        // 256 rows per block-quadrant

// ---------------------------------------------------------------------------
// Fused pass: quantize + 8-neighbor sum + u8-packed LDS joint histogram.
// Grid = B*4 (image x row-quadrant), 1024 threads. Each thread owns FOUR
// columns (float4 load = 16B/lane) and a 64-row strip: 4x the work and
// 4x the bytes per load slot vs round 3 -> covers HBM latency with ILP
// (round 3 was latency-bound at VALUBusy 23%). u8 counts safe: hottest
// per-quadrant bin lambda ~10, P(>=256) ~ 1e-300.
// ---------------------------------------------------------------------------
__global__ __launch_bounds__(1024) void fused_hist_kernel(const float* __restrict__ x,
                                                          unsigned int* __restrict__ partials,
                                                          int B) {
    __shared__ unsigned int h[HWORDS];

    const int blk  = blockIdx.x;
    const int b    = blk >> 2;
    const int quad = blk & 3;
    const int tid  = threadIdx.x;

    for (int i = tid; i < HWORDS; i += 1024) h[i] = 0u;
    __syncthreads();

    const float* img = x + (size_t)b * NPIX;
    const int c0    = (tid & 255) * 4;                  // 4 columns per thread
    const int strip = tid >> 8;                         // 0..3
    const int rs    = quad * QROWS + strip * (QROWS / 4);
    const int re    = rs + QROWS / 4;                   // 64 rows per thread
    const bool bEdge = (b == 0) || (b == B - 1);

    auto loadraw = [&](int r, float4& f, float& fl, float& fr) {
        if ((unsigned)r < IMG_H) {
            const float* row = img + r * IMG_W;
            f  = *(const float4*)(row + c0);
            fl = (c0 > 0) ? row[c0 - 1] : 0.0f;          // image left edge -> 0
            fr = (c0 + 4 < IMG_W) ? row[c0 + 4] : 0.0f;  // image right edge -> 0
        } else { f = make_float4(0.f, 0.f, 0.f, 0.f); fl = 0.f; fr = 0.f; }
    };
    auto quant6 = [&](const float4& f, float fl, float fr, int q[6]) {
        q[0] = (int)(fl  * 255.0f);
        q[1] = (int)(f.x * 255.0f);
        q[2] = (int)(f.y * 255.0f);
        q[3] = (int)(f.z * 255.0f);
        q[4] = (int)(f.w * 255.0f);
        q[5] = (int)(fr  * 255.0f);
    };

    // pipeline: hA = hsums(rs-1), hB/qB = row rs, prefetch raw row rs+1
    int hA[4], hB[4], qB[4];
    {
        float4 f; float fl, fr; loadraw(rs - 1, f, fl, fr);
        int q[6]; quant6(f, fl, fr, q);
#pragma unroll
        for (int i = 0; i < 4; ++i) hA[i] = q[i] + q[i + 1] + q[i + 2];
    }
    {
        float4 f; float fl, fr; loadraw(rs, f, fl, fr);
        int q[6]; quant6(f, fl, fr, q);
#pragma unroll
        for (int i = 0; i < 4; ++i) { hB[i] = q[i] + q[i + 1] + q[i + 2]; qB[i] = q[i + 1]; }
    }
    float4 pf; float pfl, pfr; loadraw(rs + 1, pf, pfl, pfr);

    for (int r = rs; r < re; ++r) {
        float4 cf = pf; float cfl = pfl, cfr = pfr;
        loadraw(r + 2, pf, pfl, pfr);                    // prefetch next row

        int q[6]; quant6(cf, cfl, cfr, q);
        int hC[4];
#pragma unroll
        for (int i = 0; i < 4; ++i) hC[i] = q[i] + q[i + 1] + q[i + 2];

        // divisor 5 everywhere except (batch,row) corners = 3 (reference's
        // batch-indexed normalization quirk); int div == float-trunc here.
        // r is wave-uniform (strips are wave-pure) -> scalar branch.
        const bool corner = bEdge && (r == 0 || r == IMG_H - 1);
#pragma unroll
        for (int i = 0; i < 4; ++i) {
            int nb = hA[i] + hB[i] + hC[i] - qB[i];      // 8-neighbor sum
            unsigned mean = corner ? (unsigned)nb / 3u : (unsigned)nb / 5u;
            unsigned bin  = (unsigned)qB[i] * MEANS + mean;
            atomicAdd(&h[bin >> 2], 1u << ((bin & 3u) * 8u));
            hA[i] = hB[i]; hB[i] = hC[i]; qB[i] = q[i + 1];
        }
    }
    __syncthreads();

    unsigned int* dst = partials + (size_t)blk * HWORDS;
    for (int i = tid; i < HWORDS; i += 1024) dst[i] = h[i];
}

// ---------------------------------------------------------------------------
// Merge 4 quadrant partials per image (bytewise) + entropy. One thread per
// histogram word: grid (HWORDS/256, B) -> 6848 blocks, full occupancy, no
// grid-stride loop (round 3 ran this at 4 waves/CU and was latency-bound).
// ---------------------------------------------------------------------------
__global__ __launch_bounds__(256) void merge_entropy_kernel(const unsigned int* __restrict__ partials,
                                                            double* __restrict__ acc,
                                                            int B) {
    const int w   = blockIdx.x * 256 + threadIdx.x;      // 0..HWORDS-1 exact
    const int img = blockIdx.y;
    const unsigned int* p = partials + (size_t)img * QUADS * HWORDS + w;
    unsigned w0 = p[0], w1 = p[HWORDS], w2 = p[2 * HWORDS], w3 = p[3 * HWORDS];

    double local = 0.0;
#pragma unroll
    for (int sh = 0; sh < 32; sh += 8) {
        unsigned c = ((w0 >> sh) & 255u) + ((w1 >> sh) & 255u)
                   + ((w2 >> sh) & 255u) + ((w3 >> sh) & 255u);
        if (c) local += (double)c * (20.0 - (double)log2f((float)c));
    }
    for (int off = 32; off > 0; off >>= 1)
        local += __shfl_down(local, off, 64);

    __shared__ double sacc[4];
    const int lane = threadIdx.x & 63;
    const int wid  = threadIdx.x >> 6;
    if (lane == 0) sacc[wid] = local;
    __syncthreads();
    if (threadIdx.x == 0)
        atomicAdd(acc, sacc[0] + sacc[1] + sacc[2] + sacc[3]);
}

__global__ void finalize_kernel(const double* __restrict__ acc,
                                float* __restrict__ out, int B) {
    out[0] = (float)(acc[0] / ((double)NPIX * (double)B));
}

// ---------------------------------------------------------------------------
// Fallback (round-1, validated): global-atomic histogram path.
// ---------------------------------------------------------------------------
__global__ __launch_bounds__(256) void hist_kernel(const float* __restrict__ x,
                                                   unsigned int* __restrict__ hist,
                                                   int B) {
    __shared__ int s[LW * LW];
    const int tilesPerRow = IMG_W / TILE;
    const int tilesPerImg = (IMG_H / TILE) * tilesPerRow;
    const int b   = blockIdx.x / tilesPerImg;
    const int t   = blockIdx.x % tilesPerImg;
    const int ty0 = (t / tilesPerRow) * TILE;
    const int tx0 = (t % tilesPerRow) * TILE;
    const float* img = x + (size_t)b * NPIX;
    const int tid = threadIdx.x;

    for (int i = tid; i < LW * LW; i += 256) {
        int r = i / LW, c = i - r * LW;
        int gy = ty0 + r - 1, gx = tx0 + c - 1;
        int v = 0;
        if ((unsigned)gy < IMG_H && (unsigned)gx < IMG_W)
            v = (int)(img[gy * IMG_W + gx] * 255.0f);
        s[i] = v;
    }
    __syncthreads();

    unsigned int* hb = hist + (size_t)b * NBINS;
    const bool bEdge = (b == 0) || (b == B - 1);
    const int tx = tid & 63, sy = tid >> 6;
    const int c = tx + 1, r0 = sy * 16;

    int h0, h1, m1;
    { int a = s[r0 * LW + c - 1], m = s[r0 * LW + c], d = s[r0 * LW + c + 1]; h0 = a + m + d; }
    { int a = s[(r0 + 1) * LW + c - 1], m = s[(r0 + 1) * LW + c], d = s[(r0 + 1) * LW + c + 1]; h1 = a + m + d; m1 = m; }

    for (int ry = r0; ry < r0 + 16; ++ry) {
        int a = s[(ry + 2) * LW + c - 1], m = s[(ry + 2) * LW + c], d = s[(ry + 2) * LW + c + 1];
        int h2 = a + m + d;
        int nb = h0 + h1 + h2 - m1;
        int gy = ty0 + ry;
        unsigned mean = (unsigned)nb / 5u;
        if (bEdge && (gy == 0 || gy == IMG_H - 1)) mean = (unsigned)nb / 3u;
        atomicAdd(&hb[m1 * 512 + (int)mean], 1u);
        h0 = h1; h1 = h2; m1 = m;
    }
}

__global__ __launch_bounds__(256) void entropy_kernel(const unsigned int* __restrict__ hist,
                                                      double* __restrict__ acc, int n) {
    double local = 0.0;
    const int stride = gridDim.x * 256;
    for (int i = blockIdx.x * 256 + threadIdx.x; i < n; i += stride) {
        unsigned int cv = hist[i];
        if (cv) local += (double)cv * (20.0 - (double)log2f((float)cv));
    }
    for (int off = 32; off > 0; off >>= 1)
        local += __shfl_down(local, off, 64);
    __shared__ double sacc[4];
    const int lane = threadIdx.x & 63, wid = threadIdx.x >> 6;
    if (lane == 0) sacc[wid] = local;
    __syncthreads();
    if (threadIdx.x == 0)
        atomicAdd(acc, sacc[0] + sacc[1] + sacc[2] + sacc[3]);
}

extern "C" void kernel_launch(void* const* d_in, const int* in_sizes, int n_in,
                              void* d_out, int out_size, void* d_ws, size_t ws_size,
                              hipStream_t stream) {
    const float* x = (const float*)d_in[0];
    const int B = in_sizes[0] / NPIX;   // 64

    const size_t partBytes = (size_t)B * QUADS * HWORDS * sizeof(unsigned int); // ~28 MB

    if (ws_size >= partBytes + 64) {
        unsigned int* partials = (unsigned int*)d_ws;
        double* acc = (double*)((char*)d_ws + partBytes);
        hipMemsetAsync(acc, 0, sizeof(double), stream);

        fused_hist_kernel<<<B * QUADS, 1024, 0, stream>>>(x, partials, B);
        merge_entropy_kernel<<<dim3(HWORDS / 256, B), 256, 0, stream>>>(partials, acc, B);
        finalize_kernel<<<1, 1, 0, stream>>>(acc, (float*)d_out, B);
    } else {
        unsigned int* hist = (unsigned int*)d_ws;
        const size_t histBytes = (size_t)B * NBINS * sizeof(unsigned int);
        double* acc = (double*)((char*)d_ws + histBytes);
        hipMemsetAsync(d_ws, 0, histBytes + sizeof(double), stream);

        const int tilesPerImg = (IMG_H / TILE) * (IMG_W / TILE);
        hist_kernel<<<B * tilesPerImg, 256, 0, stream>>>(x, hist, B);
        entropy_kernel<<<1024, 256, 0, stream>>>(hist, acc, B * NBINS);
        finalize_kernel<<<1, 1, 0, stream>>>(acc, (float*)d_out, B);
    }
}